// Round 3
// baseline (23466.132 us; speedup 1.0000x reference)
//
#include <hip/hip_runtime.h>

// BiLSTMTagger on MI355X (gfx950) — 256 MB workspace budget.
// Chunked pipeline (8 chunks x 64 steps per layer):
//   gemm_gx(chunk)  : gathered-A GEMM -> gx for chunk, both dirs (bwd pre-gathered)
//   lstm_scan(chunk): persistent 256-block scan, W_hh register-resident,
//                     grid barrier per step, (h,c) state in global across chunks
//   layer2: scan emits step-indexed chunk buffer; classifier = two separable
//           K=512 partial GEMMs accumulating into bias-initialized d_out.
// fp16 storage/MFMA (8x finer than bf16; magnitudes small), fp32 cell math.

typedef unsigned short u16;
typedef _Float16 f16;
typedef __attribute__((ext_vector_type(8))) _Float16 f16x8;
typedef __attribute__((ext_vector_type(4))) float f32x4;

#define TT 512
#define HH 512
#define CH 64          // steps per chunk
#define NCH 8          // chunks

__device__ __forceinline__ u16 f2h(float f) { f16 h = (f16)f; return __builtin_bit_cast(u16, h); }
__device__ __forceinline__ float h2f(u16 s) { return (float)__builtin_bit_cast(f16, s); }
__device__ __forceinline__ float sigf(float x) { return 1.f / (1.f + __expf(-x)); }
__device__ __forceinline__ float tanhf_(float x) { return 1.f - 2.f / (__expf(2.f * x) + 1.f); }
__device__ __forceinline__ f32x4 zf4() { f32x4 z; z[0]=0.f; z[1]=0.f; z[2]=0.f; z[3]=0.f; return z; }

// ---------------- utility kernels ----------------

struct CvtJob { const float* s; u16* d; int n; };
struct CvtJobs { CvtJob j[9]; };

__global__ void cvt_many(CvtJobs jobs) {
  CvtJob jb = jobs.j[blockIdx.y];
  int i = blockIdx.x * 256 + threadIdx.x;
  if (i < jb.n) jb.d[i] = f2h(jb.s[i]);
}

__global__ void embed_cast(const int* __restrict__ x, const float* __restrict__ emb,
                           u16* __restrict__ e) {
  int row = blockIdx.x;                 // b*T+t
  int tok = x[row];
  e[(size_t)row * 256 + threadIdx.x] = f2h(emb[(size_t)tok * 256 + threadIdx.x]);
}

__global__ void bias_init(float* __restrict__ o, const float* __restrict__ b, int n) {
  int i = blockIdx.x * 256 + threadIdx.x;
  if (i < n) o[i] = b[i & 63];
}

__global__ void fill_diag(float* __restrict__ o, int n, float sentinel) {
  int i = blockIdx.x * 256 + threadIdx.x;
  if (i < n) o[i] = (i == 0) ? sentinel : 0.f;
}

// ---------------- grid barrier (2-level, sense-reversing) ----------------

__device__ __forceinline__ void grid_barrier(int* bar, int nblk) {
  __syncthreads();
  if (threadIdx.x == 0) {
    __threadfence();   // release: publish h stores beyond this XCD's L2
    int* leaf = bar + (int)(blockIdx.x & 7) * 32;
    int* root = bar + 512;
    int* gen  = bar + 544;
    int g = __hip_atomic_load(gen, __ATOMIC_RELAXED, __HIP_MEMORY_SCOPE_AGENT);
    int leafN = nblk >> 3;
    if (__hip_atomic_fetch_add(leaf, 1, __ATOMIC_ACQ_REL, __HIP_MEMORY_SCOPE_AGENT) == leafN - 1) {
      __hip_atomic_store(leaf, 0, __ATOMIC_RELAXED, __HIP_MEMORY_SCOPE_AGENT);
      if (__hip_atomic_fetch_add(root, 1, __ATOMIC_ACQ_REL, __HIP_MEMORY_SCOPE_AGENT) == 7) {
        __hip_atomic_store(root, 0, __ATOMIC_RELAXED, __HIP_MEMORY_SCOPE_AGENT);
        __hip_atomic_store(gen, g + 1, __ATOMIC_RELEASE, __HIP_MEMORY_SCOPE_AGENT);
      }
    }
    while (__hip_atomic_load(gen, __ATOMIC_RELAXED, __HIP_MEMORY_SCOPE_AGENT) == g) {
      __builtin_amdgcn_s_sleep(1);
    }
    __threadfence();   // acquire
  }
  __syncthreads();
}

// ---------------- persistent BiLSTM scan, one chunk ----------------
// grid 256 x 128 thr. dir = blockIdx>>7. Per wave: 16 batches x 16 units, 4 gates.
// gxc: [dir][8192 = b*64+i][2048], step-indexed (bwd pre-gathered).
// out_pos (layer1): [b][pos][1024], valid->h at pos, invalid->0 at s (partition).
// out_chunk (layer2): [b*64+i][1024], step-indexed, garbage at invalid rows.

__global__ __launch_bounds__(128, 1) void lstm_scan(
    const u16* __restrict__ gxc, const u16* __restrict__ whh_f,
    const u16* __restrict__ whh_b, const int* __restrict__ len,
    u16* __restrict__ out_pos, u16* __restrict__ out_chunk,
    u16* __restrict__ hbuf, float* __restrict__ cbuf, int* __restrict__ bar, int s0)
{
  const int bi = blockIdx.x;
  const int dir = bi >> 7;
  const int sub = bi & 127;
  const int b_base = (sub >> 4) * 16;
  const int u_tile = (sub & 15) * 2 + (threadIdx.x >> 6);
  const int u_base = u_tile * 16;
  const int lane = threadIdx.x & 63;
  const int m16 = lane & 15, quad = lane >> 4;
  const u16* gxd = gxc + (size_t)dir * 8192 * 2048;
  const u16* whh = dir ? whh_b : whh_f;
  u16* hbd = hbuf + (size_t)dir * 2 * (128 * HH);

  // W_hh fragments: B[n=lane&15][k=quad*8+j], rows g*512 + u_base + n. 256 VGPRs.
  f16x8 bf[4][16];
#pragma unroll
  for (int g = 0; g < 4; ++g) {
    const u16* wrow = whh + (size_t)(g * HH + u_base + m16) * HH + quad * 8;
#pragma unroll
    for (int ks = 0; ks < 16; ++ks)
      bf[g][ks] = *(const f16x8*)(wrow + ks * 32);
  }

  int lenr[4];
#pragma unroll
  for (int r = 0; r < 4; ++r) lenr[r] = len[b_base + quad * 4 + r];

  float cst[4];
  if (s0 == 0) {
#pragma unroll
    for (int r = 0; r < 4; ++r) {
      cst[r] = 0.f;
      hbd[(b_base + quad * 4 + r) * HH + u_base + m16] = 0;   // zero h ping 0
    }
    grid_barrier(bar, (int)gridDim.x);
  } else {
#pragma unroll
    for (int r = 0; r < 4; ++r)
      cst[r] = cbuf[(size_t)dir * 65536 + (b_base + quad * 4 + r) * HH + u_base + m16];
  }

  for (int i = 0; i < CH; ++i) {
    const int s = s0 + i;
    const u16* cur = hbd + (s & 1) * (128 * HH);
    u16* nxt = hbd + ((s + 1) & 1) * (128 * HH);
    f32x4 a0 = zf4(), a1 = zf4(), a2 = zf4(), a3 = zf4();
    const u16* arow = cur + (b_base + m16) * HH + quad * 8;   // A[m=lane&15][k]
#pragma unroll
    for (int ks = 0; ks < 16; ++ks) {
      f16x8 a = *(const f16x8*)(arow + ks * 32);
      a0 = __builtin_amdgcn_mfma_f32_16x16x32_f16(a, bf[0][ks], a0, 0, 0, 0);
      a1 = __builtin_amdgcn_mfma_f32_16x16x32_f16(a, bf[1][ks], a1, 0, 0, 0);
      a2 = __builtin_amdgcn_mfma_f32_16x16x32_f16(a, bf[2][ks], a2, 0, 0, 0);
      a3 = __builtin_amdgcn_mfma_f32_16x16x32_f16(a, bf[3][ks], a3, 0, 0, 0);
    }
#pragma unroll
    for (int r = 0; r < 4; ++r) {
      const int batch = b_base + quad * 4 + r;    // C/D row = quad*4+reg
      const int L = lenr[r];
      const bool valid = s < L;
      const u16* gq = gxd + (size_t)(batch * CH + i) * 2048 + u_base + m16;
      float gi = a0[r] + h2f(gq[0]);
      float gf = a1[r] + h2f(gq[512]);
      float gg = a2[r] + h2f(gq[1024]);
      float go = a3[r] + h2f(gq[1536]);
      float c = sigf(gf) * cst[r] + sigf(gi) * tanhf_(gg);
      cst[r] = c;
      float h = sigf(go) * tanhf_(c);
      u16 hv = f2h(h);
      nxt[batch * HH + u_base + m16] = hv;
      if (out_pos) {
        const int p = dir ? (L - 1 - s) : s;
        const int wrow = valid ? (p < 0 ? 0 : p) : s;
        out_pos[(size_t)(batch * TT + wrow) * 1024 + dir * 512 + u_base + m16]
            = valid ? hv : (u16)0;
      } else {
        out_chunk[(size_t)(batch * CH + i) * 1024 + dir * 512 + u_base + m16] = hv;
      }
    }
    if (i != CH - 1) grid_barrier(bar, (int)gridDim.x);
  }

#pragma unroll
  for (int r = 0; r < 4; ++r)
    cbuf[(size_t)dir * 65536 + (b_base + quad * 4 + r) * HH + u_base + m16] = cst[r];
}

// ---------------- gx GEMM (gathered A rows): gxc[dir][m][n] = A[row(m)] @ B[n]^T + bias
// M=8192 (b*64+i), N=2048, K in {256,1024}. fwd row = b*T+s ; bwd row = b*T+clamp(L-1-s).

__global__ __launch_bounds__(256) void gemm_gx(
    const u16* __restrict__ A, const u16* __restrict__ Bf, const u16* __restrict__ Bb,
    const float* __restrict__ biasf, const float* __restrict__ biasb,
    u16* __restrict__ gxc, const int* __restrict__ len, int s0, int K)
{
  const int dir = blockIdx.z;
  const u16* Bm = dir ? Bb : Bf;
  const float* bias = dir ? biasb : biasf;
  u16* Cp = gxc + (size_t)dir * 8192 * 2048;
  __shared__ u16 As[128 * 40];
  __shared__ u16 Bs[128 * 40];
  const int tid = threadIdx.x;
  const int lane = tid & 63;
  const int wv = tid >> 6;
  const int wr = (wv >> 1) * 64, wc = (wv & 1) * 64;
  const int m16 = lane & 15, quad = lane >> 4;
  const int rowst = tid >> 1;
  const int offst = (tid & 1) * 16;
  const int m0 = blockIdx.x * 128;
  const int n0 = blockIdx.y * 128;

  // gathered A row for this thread's staging row
  const int m = m0 + rowst;
  const int b = m >> 6, i = m & 63, s = s0 + i;
  int pos;
  if (dir) { int p = len[b] - 1 - s; pos = p < 0 ? 0 : p; } else { pos = s; }
  const u16* Arow = A + ((size_t)b * TT + pos) * K;
  const u16* Brow = Bm + (size_t)(n0 + rowst) * K;

  f32x4 acc[4][4];
#pragma unroll
  for (int a = 0; a < 4; ++a)
#pragma unroll
    for (int c = 0; c < 4; ++c) acc[a][c] = zf4();

  for (int kt = 0; kt < K; kt += 32) {
    *(uint4*)&As[rowst * 40 + offst]     = *(const uint4*)(Arow + kt + offst);
    *(uint4*)&As[rowst * 40 + offst + 8] = *(const uint4*)(Arow + kt + offst + 8);
    *(uint4*)&Bs[rowst * 40 + offst]     = *(const uint4*)(Brow + kt + offst);
    *(uint4*)&Bs[rowst * 40 + offst + 8] = *(const uint4*)(Brow + kt + offst + 8);
    __syncthreads();
    f16x8 af[4], bfr[4];
#pragma unroll
    for (int mt = 0; mt < 4; ++mt)
      af[mt] = *(const f16x8*)&As[(wr + mt * 16 + m16) * 40 + quad * 8];
#pragma unroll
    for (int nt = 0; nt < 4; ++nt)
      bfr[nt] = *(const f16x8*)&Bs[(wc + nt * 16 + m16) * 40 + quad * 8];
#pragma unroll
    for (int mt = 0; mt < 4; ++mt)
#pragma unroll
      for (int nt = 0; nt < 4; ++nt)
        acc[mt][nt] = __builtin_amdgcn_mfma_f32_16x16x32_f16(af[mt], bfr[nt], acc[mt][nt], 0, 0, 0);
    __syncthreads();
  }

#pragma unroll
  for (int mt = 0; mt < 4; ++mt)
#pragma unroll
    for (int nt = 0; nt < 4; ++nt) {
      const int n = n0 + wc + nt * 16 + m16;
      const float bv = bias[n];
#pragma unroll
      for (int r = 0; r < 4; ++r) {
        const int mm = m0 + wr + mt * 16 + quad * 4 + r;
        Cp[(size_t)mm * 2048 + n] = f2h(acc[mt][nt][r] + bv);
      }
    }
}

// ---------------- classifier partial GEMM (K=512 half), accumulate into d_out
// A = out2c[.][dir*512 + k] (step-indexed), C row = b*T + pos(s,dir), skip invalid.

__global__ __launch_bounds__(256) void gemm_cls(
    const u16* __restrict__ out2c, const u16* __restrict__ wcls,
    float* __restrict__ dout, const int* __restrict__ len, int s0)
{
  const int dir = blockIdx.z;
  __shared__ u16 As[128 * 40];
  __shared__ u16 Bs[128 * 40];
  const int tid = threadIdx.x;
  const int lane = tid & 63;
  const int wv = tid >> 6;
  const int wr = (wv >> 1) * 64, wc = (wv & 1) * 64;
  const int m16 = lane & 15, quad = lane >> 4;
  const int rowst = tid >> 1;
  const int offst = (tid & 1) * 16;
  const int m0 = blockIdx.x * 128;
  const u16* Arow = out2c + (size_t)(m0 + rowst) * 1024 + dir * 512;
  const int rowb = rowst < 64 ? rowst : 63;
  const u16* Brow = wcls + (size_t)rowb * 1024 + dir * 512;

  f32x4 acc[4][4];
#pragma unroll
  for (int a = 0; a < 4; ++a)
#pragma unroll
    for (int c = 0; c < 4; ++c) acc[a][c] = zf4();

  for (int kt = 0; kt < 512; kt += 32) {
    *(uint4*)&As[rowst * 40 + offst]     = *(const uint4*)(Arow + kt + offst);
    *(uint4*)&As[rowst * 40 + offst + 8] = *(const uint4*)(Arow + kt + offst + 8);
    *(uint4*)&Bs[rowst * 40 + offst]     = *(const uint4*)(Brow + kt + offst);
    *(uint4*)&Bs[rowst * 40 + offst + 8] = *(const uint4*)(Brow + kt + offst + 8);
    __syncthreads();
    f16x8 af[4], bfr[4];
#pragma unroll
    for (int mt = 0; mt < 4; ++mt)
      af[mt] = *(const f16x8*)&As[(wr + mt * 16 + m16) * 40 + quad * 8];
#pragma unroll
    for (int nt = 0; nt < 4; ++nt)
      bfr[nt] = *(const f16x8*)&Bs[(wc + nt * 16 + m16) * 40 + quad * 8];
#pragma unroll
    for (int mt = 0; mt < 4; ++mt)
#pragma unroll
      for (int nt = 0; nt < 4; ++nt)
        acc[mt][nt] = __builtin_amdgcn_mfma_f32_16x16x32_f16(af[mt], bfr[nt], acc[mt][nt], 0, 0, 0);
    __syncthreads();
  }

#pragma unroll
  for (int mt = 0; mt < 4; ++mt)
#pragma unroll
    for (int nt = 0; nt < 4; ++nt) {
      const int n = wc + nt * 16 + m16;
      if (n < 64) {
#pragma unroll
        for (int r = 0; r < 4; ++r) {
          const int m = m0 + wr + mt * 16 + quad * 4 + r;
          const int b = m >> 6, i = m & 63, s = s0 + i;
          const int L = len[b];
          if (s < L) {
            const int pos = dir ? (L - 1 - s) : s;
            atomicAdd(&dout[((size_t)b * TT + pos) * 64 + n], acc[mt][nt][r]);
          }
        }
      }
    }
}

// ---------------- launch ----------------

extern "C" void kernel_launch(void* const* d_in, const int* in_sizes, int n_in,
                              void* d_out, int out_size, void* d_ws, size_t ws_size,
                              hipStream_t stream) {
  const int*   x      = (const int*)d_in[0];
  const int*   len    = (const int*)d_in[1];
  const float* emb    = (const float*)d_in[2];
  const float* Wih_f1 = (const float*)d_in[3];
  const float* Whh_f1 = (const float*)d_in[4];
  const float* b_f1   = (const float*)d_in[5];
  const float* Wih_b1 = (const float*)d_in[6];
  const float* Whh_b1 = (const float*)d_in[7];
  const float* b_b1   = (const float*)d_in[8];
  const float* Wih_f2 = (const float*)d_in[9];
  const float* Whh_f2 = (const float*)d_in[10];
  const float* b_f2   = (const float*)d_in[11];
  const float* Wih_b2 = (const float*)d_in[12];
  const float* Whh_b2 = (const float*)d_in[13];
  const float* b_b2   = (const float*)d_in[14];
  const float* W_cls  = (const float*)d_in[15];
  const float* b_cls  = (const float*)d_in[16];

  const size_t GXC  = (size_t)2 * 8192 * 2048 * 2;     // 64 MB
  const size_t OUT1 = (size_t)65536 * 1024 * 2;        // 128 MB
  const size_t EREG = (size_t)65536 * 256 * 2;         // 32 MB (also out2 chunk 16 MB)
  const size_t WTS  = (size_t)9502720 * 2;             // 18.1 MB
  const size_t NEED = GXC + OUT1 + EREG + WTS + 524288 + 524288 + 4096;
  if (ws_size < NEED) {
    fill_diag<<<dim3((out_size + 255) / 256), dim3(256), 0, stream>>>(
        (float*)d_out, out_size, (float)(ws_size >> 20));
    return;
  }

  char* w = (char*)d_ws;
  u16* gxc   = (u16*)w; w += GXC;
  u16* out1  = (u16*)w; w += OUT1;
  u16* ereg  = (u16*)w; w += EREG;     // e (layer1) -> out2 chunk (layer2)
  u16* wihf1 = (u16*)w; w += (size_t)2048 * 256 * 2;
  u16* wihb1 = (u16*)w; w += (size_t)2048 * 256 * 2;
  u16* whhf1 = (u16*)w; w += (size_t)2048 * 512 * 2;
  u16* whhb1 = (u16*)w; w += (size_t)2048 * 512 * 2;
  u16* wihf2 = (u16*)w; w += (size_t)2048 * 1024 * 2;
  u16* wihb2 = (u16*)w; w += (size_t)2048 * 1024 * 2;
  u16* whhf2 = (u16*)w; w += (size_t)2048 * 512 * 2;
  u16* whhb2 = (u16*)w; w += (size_t)2048 * 512 * 2;
  u16* wcls  = (u16*)w; w += (size_t)64 * 1024 * 2;
  u16* hbuf  = (u16*)w; w += 524288;
  float* cbuf = (float*)w; w += 524288;
  int* bar   = (int*)w; w += 4096;

  u16* e     = ereg;
  u16* out2c = ereg;   // 8192*1024*2 = 16 MB, live only in layer 2

  CvtJobs jobs = {{
    { Wih_f1, wihf1, 2048 * 256 }, { Wih_b1, wihb1, 2048 * 256 },
    { Whh_f1, whhf1, 2048 * 512 }, { Whh_b1, whhb1, 2048 * 512 },
    { Wih_f2, wihf2, 2048 * 1024 }, { Wih_b2, wihb2, 2048 * 1024 },
    { Whh_f2, whhf2, 2048 * 512 }, { Whh_b2, whhb2, 2048 * 512 },
    { W_cls,  wcls,  64 * 1024 },
  }};
  cvt_many<<<dim3(8192, 9), dim3(256), 0, stream>>>(jobs);
  embed_cast<<<dim3(65536), dim3(256), 0, stream>>>(x, emb, e);
  bias_init<<<dim3(16384), dim3(256), 0, stream>>>((float*)d_out, b_cls, 65536 * 64);
  hipMemsetAsync(bar, 0, 4096, stream);

  // layer 1
  for (int c = 0; c < NCH; ++c) {
    gemm_gx<<<dim3(64, 16, 2), dim3(256), 0, stream>>>(
        e, wihf1, wihb1, b_f1, b_b1, gxc, len, c * CH, 256);
    lstm_scan<<<dim3(256), dim3(128), 0, stream>>>(
        gxc, whhf1, whhb1, len, out1, nullptr, hbuf, cbuf, bar, c * CH);
  }
  // layer 2 (+ chunked classifier)
  for (int c = 0; c < NCH; ++c) {
    gemm_gx<<<dim3(64, 16, 2), dim3(256), 0, stream>>>(
        out1, wihf2, wihb2, b_f2, b_b2, gxc, len, c * CH, 1024);
    lstm_scan<<<dim3(256), dim3(128), 0, stream>>>(
        gxc, whhf2, whhb2, len, nullptr, out2c, hbuf, cbuf, bar, c * CH);
    gemm_cls<<<dim3(64, 1, 2), dim3(256), 0, stream>>>(
        out2c, wcls, (float*)d_out, len, c * CH);
  }
}

// Round 4
// 11463.795 us; speedup vs baseline: 2.0470x; 2.0470x over previous
//
#include <hip/hip_runtime.h>

// BiLSTMTagger on MI355X (gfx950) — 256 MB workspace budget.
// Chunked pipeline (8 chunks x 64 steps per layer):
//   gemm_gx(chunk)  : gathered-A GEMM -> gx for chunk, both dirs (bwd pre-gathered)
//   lstm_scan(chunk): persistent 256-block scan, W_hh register/AGPR-resident,
//                     fence-free grid barrier per step (h travels via LLC:
//                     agent-scope sc1 stores/loads), (h,c) state across chunks
//   layer2: scan emits step-indexed chunk buffer; classifier = two separable
//           K=512 partial GEMMs accumulating into bias-initialized d_out.
// fp16 storage/MFMA, fp32 cell math.

typedef unsigned short u16;
typedef unsigned long long u64;
typedef _Float16 f16;
typedef __attribute__((ext_vector_type(8))) _Float16 f16x8;
typedef __attribute__((ext_vector_type(4))) float f32x4;

#define TT 512
#define HH 512
#define CH 64          // steps per chunk
#define NCH 8          // chunks

__device__ __forceinline__ u16 f2h(float f) { f16 h = (f16)f; return __builtin_bit_cast(u16, h); }
__device__ __forceinline__ float h2f(u16 s) { return (float)__builtin_bit_cast(f16, s); }
__device__ __forceinline__ float sigf(float x) { return 1.f / (1.f + __expf(-x)); }
__device__ __forceinline__ float tanhf_(float x) { return 1.f - 2.f / (__expf(2.f * x) + 1.f); }
__device__ __forceinline__ f32x4 zf4() { f32x4 z; z[0]=0.f; z[1]=0.f; z[2]=0.f; z[3]=0.f; return z; }

// LLC-coherent h transport: stores/loads at agent scope (sc1) bypass the
// non-coherent per-XCD L2, so NO __threadfence (L2 writeback) is ever needed.
__device__ __forceinline__ void store_h(u16* p, u16 v) {
  __hip_atomic_store(p, v, __ATOMIC_RELAXED, __HIP_MEMORY_SCOPE_AGENT);
}
__device__ __forceinline__ f16x8 load_h16(const u16* p) {
  union { u64 q[2]; f16x8 v; } u;
  u.q[0] = __hip_atomic_load((const u64*)p,     __ATOMIC_RELAXED, __HIP_MEMORY_SCOPE_AGENT);
  u.q[1] = __hip_atomic_load((const u64*)p + 1, __ATOMIC_RELAXED, __HIP_MEMORY_SCOPE_AGENT);
  return u.v;
}

// ---------------- utility kernels ----------------

struct CvtJob { const float* s; u16* d; int n; };
struct CvtJobs { CvtJob j[9]; };

__global__ void cvt_many(CvtJobs jobs) {
  CvtJob jb = jobs.j[blockIdx.y];
  int i = blockIdx.x * 256 + threadIdx.x;
  if (i < jb.n) jb.d[i] = f2h(jb.s[i]);
}

__global__ void embed_cast(const int* __restrict__ x, const float* __restrict__ emb,
                           u16* __restrict__ e) {
  int row = blockIdx.x;                 // b*T+t
  int tok = x[row];
  e[(size_t)row * 256 + threadIdx.x] = f2h(emb[(size_t)tok * 256 + threadIdx.x]);
}

__global__ void bias_init(float* __restrict__ o, const float* __restrict__ b, int n) {
  int i = blockIdx.x * 256 + threadIdx.x;
  if (i < n) o[i] = b[i & 63];
}

__global__ void fill_diag(float* __restrict__ o, int n, float sentinel) {
  int i = blockIdx.x * 256 + threadIdx.x;
  if (i < n) o[i] = (i == 0) ? sentinel : 0.f;
}

// ---------------- fence-free grid barrier (monotone 2-level tree) ----------------
// bar ints: 16 leaves at [i*32], root at [512], flag at [544]. All counters are
// monotone (no resets -> no ABA). Generation G supplied by caller (same count
// in every block). One s_waitcnt vmcnt(0) orders this block's sc1 h-stores
// (complete at LLC) before arrival; flag visibility then implies h visibility.

__device__ __forceinline__ void grid_barrier(int* bar, int G) {
  __syncthreads();
  if (threadIdx.x == 0) {
    asm volatile("s_waitcnt vmcnt(0)" ::: "memory");
    int* leaf = bar + (int)(blockIdx.x & 15) * 32;
    int* root = bar + 512;
    int* flag = bar + 544;
    if (__hip_atomic_fetch_add(leaf, 1, __ATOMIC_RELAXED, __HIP_MEMORY_SCOPE_AGENT)
        == 16 * (G + 1) - 1) {
      if (__hip_atomic_fetch_add(root, 1, __ATOMIC_RELAXED, __HIP_MEMORY_SCOPE_AGENT)
          == 16 * (G + 1) - 1) {
        __hip_atomic_store(flag, G + 1, __ATOMIC_RELAXED, __HIP_MEMORY_SCOPE_AGENT);
      }
    }
    while (__hip_atomic_load(flag, __ATOMIC_RELAXED, __HIP_MEMORY_SCOPE_AGENT) < G + 1)
      __builtin_amdgcn_s_sleep(1);
    asm volatile("" ::: "memory");
  }
  __syncthreads();
}

// ---------------- persistent BiLSTM scan, one chunk ----------------
// grid 256 x 128 thr. dir = blockIdx>>7. Per wave: 16 batches x 16 units, 4 gates.
// gxc: [dir][8192 = b*64+i][2048], step-indexed (bwd pre-gathered).
// out_pos (layer1): [b][pos][1024]; out_chunk (layer2): [b*64+i][1024].

__global__ __launch_bounds__(128, 1) void lstm_scan(
    const u16* __restrict__ gxc, const u16* __restrict__ whh_f,
    const u16* __restrict__ whh_b, const int* __restrict__ len,
    u16* __restrict__ out_pos, u16* __restrict__ out_chunk,
    u16* __restrict__ hbuf, float* __restrict__ cbuf, int* __restrict__ bar,
    int s0, int gen0)
{
  const int bi = blockIdx.x;
  const int dir = bi >> 7;
  const int sub = bi & 127;
  const int b_base = (sub >> 4) * 16;
  const int u_tile = (sub & 15) * 2 + (threadIdx.x >> 6);
  const int u_base = u_tile * 16;
  const int lane = threadIdx.x & 63;
  const int m16 = lane & 15, quad = lane >> 4;
  const u16* gxd = gxc + (size_t)dir * 8192 * 2048;
  const u16* whh = dir ? whh_b : whh_f;
  u16* hbd = hbuf + (size_t)dir * 2 * (128 * HH);

  // W_hh fragments: B[n=lane&15][k=quad*8+j], rows g*512 + u_base + n.
  // 64 f16x8 = 256 regs -> compiler places in AGPRs (gfx950 unified file).
  f16x8 bf[4][16];
#pragma unroll
  for (int g = 0; g < 4; ++g) {
    const u16* wrow = whh + (size_t)(g * HH + u_base + m16) * HH + quad * 8;
#pragma unroll
    for (int ks = 0; ks < 16; ++ks)
      bf[g][ks] = *(const f16x8*)(wrow + ks * 32);
  }

  int lenr[4];
#pragma unroll
  for (int r = 0; r < 4; ++r) lenr[r] = len[b_base + quad * 4 + r];

  int G = gen0;
  float cst[4];
  if (s0 == 0) {
#pragma unroll
    for (int r = 0; r < 4; ++r) {
      cst[r] = 0.f;
      store_h(&hbd[(b_base + quad * 4 + r) * HH + u_base + m16], 0);
    }
    grid_barrier(bar, G++);
  } else {
#pragma unroll
    for (int r = 0; r < 4; ++r)
      cst[r] = cbuf[(size_t)dir * 65536 + (b_base + quad * 4 + r) * HH + u_base + m16];
  }

  for (int i = 0; i < CH; ++i) {
    const int s = s0 + i;
    const u16* cur = hbd + (s & 1) * (128 * HH);
    u16* nxt = hbd + ((s + 1) & 1) * (128 * HH);
    f32x4 a0 = zf4(), a1 = zf4(), a2 = zf4(), a3 = zf4();
    const u16* arow = cur + (b_base + m16) * HH + quad * 8;   // A[m=lane&15][k]
#pragma unroll
    for (int ks = 0; ks < 16; ++ks) {
      f16x8 a = load_h16(arow + ks * 32);
      a0 = __builtin_amdgcn_mfma_f32_16x16x32_f16(a, bf[0][ks], a0, 0, 0, 0);
      a1 = __builtin_amdgcn_mfma_f32_16x16x32_f16(a, bf[1][ks], a1, 0, 0, 0);
      a2 = __builtin_amdgcn_mfma_f32_16x16x32_f16(a, bf[2][ks], a2, 0, 0, 0);
      a3 = __builtin_amdgcn_mfma_f32_16x16x32_f16(a, bf[3][ks], a3, 0, 0, 0);
    }
#pragma unroll
    for (int r = 0; r < 4; ++r) {
      const int batch = b_base + quad * 4 + r;    // C/D row = quad*4+reg
      const int L = lenr[r];
      const bool valid = s < L;
      const u16* gq = gxd + (size_t)(batch * CH + i) * 2048 + u_base + m16;
      float gi = a0[r] + h2f(gq[0]);
      float gf = a1[r] + h2f(gq[512]);
      float gg = a2[r] + h2f(gq[1024]);
      float go = a3[r] + h2f(gq[1536]);
      float c = sigf(gf) * cst[r] + sigf(gi) * tanhf_(gg);
      cst[r] = c;
      float h = sigf(go) * tanhf_(c);
      u16 hv = f2h(h);
      store_h(&nxt[batch * HH + u_base + m16], hv);
      if (out_pos) {
        const int p = dir ? (L - 1 - s) : s;
        const int wrow = valid ? (p < 0 ? 0 : p) : s;
        out_pos[(size_t)(batch * TT + wrow) * 1024 + dir * 512 + u_base + m16]
            = valid ? hv : (u16)0;
      } else {
        out_chunk[(size_t)(batch * CH + i) * 1024 + dir * 512 + u_base + m16] = hv;
      }
    }
    if (i != CH - 1) grid_barrier(bar, G++);
  }

#pragma unroll
  for (int r = 0; r < 4; ++r)
    cbuf[(size_t)dir * 65536 + (b_base + quad * 4 + r) * HH + u_base + m16] = cst[r];
}

// ---------------- gx GEMM (gathered A rows): gxc[dir][m][n] = A[row(m)] @ B[n]^T + bias
// M=8192 (b*64+i), N=2048, K in {256,1024}. fwd row = b*T+s ; bwd row = b*T+clamp(L-1-s).

__global__ __launch_bounds__(256) void gemm_gx(
    const u16* __restrict__ A, const u16* __restrict__ Bf, const u16* __restrict__ Bb,
    const float* __restrict__ biasf, const float* __restrict__ biasb,
    u16* __restrict__ gxc, const int* __restrict__ len, int s0, int K)
{
  const int dir = blockIdx.z;
  const u16* Bm = dir ? Bb : Bf;
  const float* bias = dir ? biasb : biasf;
  u16* Cp = gxc + (size_t)dir * 8192 * 2048;
  __shared__ u16 As[128 * 40];
  __shared__ u16 Bs[128 * 40];
  const int tid = threadIdx.x;
  const int lane = tid & 63;
  const int wv = tid >> 6;
  const int wr = (wv >> 1) * 64, wc = (wv & 1) * 64;
  const int m16 = lane & 15, quad = lane >> 4;
  const int rowst = tid >> 1;
  const int offst = (tid & 1) * 16;
  const int m0 = blockIdx.x * 128;
  const int n0 = blockIdx.y * 128;

  const int m = m0 + rowst;
  const int b = m >> 6, i = m & 63, s = s0 + i;
  int pos;
  if (dir) { int p = len[b] - 1 - s; pos = p < 0 ? 0 : p; } else { pos = s; }
  const u16* Arow = A + ((size_t)b * TT + pos) * K;
  const u16* Brow = Bm + (size_t)(n0 + rowst) * K;

  f32x4 acc[4][4];
#pragma unroll
  for (int a = 0; a < 4; ++a)
#pragma unroll
    for (int c = 0; c < 4; ++c) acc[a][c] = zf4();

  for (int kt = 0; kt < K; kt += 32) {
    *(uint4*)&As[rowst * 40 + offst]     = *(const uint4*)(Arow + kt + offst);
    *(uint4*)&As[rowst * 40 + offst + 8] = *(const uint4*)(Arow + kt + offst + 8);
    *(uint4*)&Bs[rowst * 40 + offst]     = *(const uint4*)(Brow + kt + offst);
    *(uint4*)&Bs[rowst * 40 + offst + 8] = *(const uint4*)(Brow + kt + offst + 8);
    __syncthreads();
    f16x8 af[4], bfr[4];
#pragma unroll
    for (int mt = 0; mt < 4; ++mt)
      af[mt] = *(const f16x8*)&As[(wr + mt * 16 + m16) * 40 + quad * 8];
#pragma unroll
    for (int nt = 0; nt < 4; ++nt)
      bfr[nt] = *(const f16x8*)&Bs[(wc + nt * 16 + m16) * 40 + quad * 8];
#pragma unroll
    for (int mt = 0; mt < 4; ++mt)
#pragma unroll
      for (int nt = 0; nt < 4; ++nt)
        acc[mt][nt] = __builtin_amdgcn_mfma_f32_16x16x32_f16(af[mt], bfr[nt], acc[mt][nt], 0, 0, 0);
    __syncthreads();
  }

#pragma unroll
  for (int mt = 0; mt < 4; ++mt)
#pragma unroll
    for (int nt = 0; nt < 4; ++nt) {
      const int n = n0 + wc + nt * 16 + m16;
      const float bv = bias[n];
#pragma unroll
      for (int r = 0; r < 4; ++r) {
        const int mm = m0 + wr + mt * 16 + quad * 4 + r;
        Cp[(size_t)mm * 2048 + n] = f2h(acc[mt][nt][r] + bv);
      }
    }
}

// ---------------- classifier partial GEMM (K=512 half), accumulate into d_out

__global__ __launch_bounds__(256) void gemm_cls(
    const u16* __restrict__ out2c, const u16* __restrict__ wcls,
    float* __restrict__ dout, const int* __restrict__ len, int s0)
{
  const int dir = blockIdx.z;
  __shared__ u16 As[128 * 40];
  __shared__ u16 Bs[128 * 40];
  const int tid = threadIdx.x;
  const int lane = tid & 63;
  const int wv = tid >> 6;
  const int wr = (wv >> 1) * 64, wc = (wv & 1) * 64;
  const int m16 = lane & 15, quad = lane >> 4;
  const int rowst = tid >> 1;
  const int offst = (tid & 1) * 16;
  const int m0 = blockIdx.x * 128;
  const u16* Arow = out2c + (size_t)(m0 + rowst) * 1024 + dir * 512;
  const int rowb = rowst < 64 ? rowst : 63;
  const u16* Brow = wcls + (size_t)rowb * 1024 + dir * 512;

  f32x4 acc[4][4];
#pragma unroll
  for (int a = 0; a < 4; ++a)
#pragma unroll
    for (int c = 0; c < 4; ++c) acc[a][c] = zf4();

  for (int kt = 0; kt < 512; kt += 32) {
    *(uint4*)&As[rowst * 40 + offst]     = *(const uint4*)(Arow + kt + offst);
    *(uint4*)&As[rowst * 40 + offst + 8] = *(const uint4*)(Arow + kt + offst + 8);
    *(uint4*)&Bs[rowst * 40 + offst]     = *(const uint4*)(Brow + kt + offst);
    *(uint4*)&Bs[rowst * 40 + offst + 8] = *(const uint4*)(Brow + kt + offst + 8);
    __syncthreads();
    f16x8 af[4], bfr[4];
#pragma unroll
    for (int mt = 0; mt < 4; ++mt)
      af[mt] = *(const f16x8*)&As[(wr + mt * 16 + m16) * 40 + quad * 8];
#pragma unroll
    for (int nt = 0; nt < 4; ++nt)
      bfr[nt] = *(const f16x8*)&Bs[(wc + nt * 16 + m16) * 40 + quad * 8];
#pragma unroll
    for (int mt = 0; mt < 4; ++mt)
#pragma unroll
      for (int nt = 0; nt < 4; ++nt)
        acc[mt][nt] = __builtin_amdgcn_mfma_f32_16x16x32_f16(af[mt], bfr[nt], acc[mt][nt], 0, 0, 0);
    __syncthreads();
  }

#pragma unroll
  for (int mt = 0; mt < 4; ++mt)
#pragma unroll
    for (int nt = 0; nt < 4; ++nt) {
      const int n = wc + nt * 16 + m16;
      if (n < 64) {
#pragma unroll
        for (int r = 0; r < 4; ++r) {
          const int m = m0 + wr + mt * 16 + quad * 4 + r;
          const int b = m >> 6, i = m & 63, s = s0 + i;
          const int L = len[b];
          if (s < L) {
            const int pos = dir ? (L - 1 - s) : s;
            atomicAdd(&dout[((size_t)b * TT + pos) * 64 + n], acc[mt][nt][r]);
          }
        }
      }
    }
}

// ---------------- launch ----------------

extern "C" void kernel_launch(void* const* d_in, const int* in_sizes, int n_in,
                              void* d_out, int out_size, void* d_ws, size_t ws_size,
                              hipStream_t stream) {
  const int*   x      = (const int*)d_in[0];
  const int*   len    = (const int*)d_in[1];
  const float* emb    = (const float*)d_in[2];
  const float* Wih_f1 = (const float*)d_in[3];
  const float* Whh_f1 = (const float*)d_in[4];
  const float* b_f1   = (const float*)d_in[5];
  const float* Wih_b1 = (const float*)d_in[6];
  const float* Whh_b1 = (const float*)d_in[7];
  const float* b_b1   = (const float*)d_in[8];
  const float* Wih_f2 = (const float*)d_in[9];
  const float* Whh_f2 = (const float*)d_in[10];
  const float* b_f2   = (const float*)d_in[11];
  const float* Wih_b2 = (const float*)d_in[12];
  const float* Whh_b2 = (const float*)d_in[13];
  const float* b_b2   = (const float*)d_in[14];
  const float* W_cls  = (const float*)d_in[15];
  const float* b_cls  = (const float*)d_in[16];

  const size_t GXC  = (size_t)2 * 8192 * 2048 * 2;     // 64 MB
  const size_t OUT1 = (size_t)65536 * 1024 * 2;        // 128 MB
  const size_t EREG = (size_t)65536 * 256 * 2;         // 32 MB (also out2 chunk 16 MB)
  const size_t WTS  = (size_t)9502720 * 2;             // 18.1 MB
  const size_t NEED = GXC + OUT1 + EREG + WTS + 524288 + 524288 + 4096;
  if (ws_size < NEED) {
    fill_diag<<<dim3((out_size + 255) / 256), dim3(256), 0, stream>>>(
        (float*)d_out, out_size, (float)(ws_size >> 20));
    return;
  }

  char* w = (char*)d_ws;
  u16* gxc   = (u16*)w; w += GXC;
  u16* out1  = (u16*)w; w += OUT1;
  u16* ereg  = (u16*)w; w += EREG;     // e (layer1) -> out2 chunk (layer2)
  u16* wihf1 = (u16*)w; w += (size_t)2048 * 256 * 2;
  u16* wihb1 = (u16*)w; w += (size_t)2048 * 256 * 2;
  u16* whhf1 = (u16*)w; w += (size_t)2048 * 512 * 2;
  u16* whhb1 = (u16*)w; w += (size_t)2048 * 512 * 2;
  u16* wihf2 = (u16*)w; w += (size_t)2048 * 1024 * 2;
  u16* wihb2 = (u16*)w; w += (size_t)2048 * 1024 * 2;
  u16* whhf2 = (u16*)w; w += (size_t)2048 * 512 * 2;
  u16* whhb2 = (u16*)w; w += (size_t)2048 * 512 * 2;
  u16* wcls  = (u16*)w; w += (size_t)64 * 1024 * 2;
  u16* hbuf  = (u16*)w; w += 524288;
  float* cbuf = (float*)w; w += 524288;
  int* bar   = (int*)w; w += 4096;

  u16* e     = ereg;
  u16* out2c = ereg;   // 16 MB, live only in layer 2

  CvtJobs jobs = {{
    { Wih_f1, wihf1, 2048 * 256 }, { Wih_b1, wihb1, 2048 * 256 },
    { Whh_f1, whhf1, 2048 * 512 }, { Whh_b1, whhb1, 2048 * 512 },
    { Wih_f2, wihf2, 2048 * 1024 }, { Wih_b2, wihb2, 2048 * 1024 },
    { Whh_f2, whhf2, 2048 * 512 }, { Whh_b2, whhb2, 2048 * 512 },
    { W_cls,  wcls,  64 * 1024 },
  }};
  cvt_many<<<dim3(8192, 9), dim3(256), 0, stream>>>(jobs);
  embed_cast<<<dim3(65536), dim3(256), 0, stream>>>(x, emb, e);
  bias_init<<<dim3(16384), dim3(256), 0, stream>>>((float*)d_out, b_cls, 65536 * 64);
  hipMemsetAsync(bar, 0, 4096, stream);

  int g0 = 0;
  // layer 1
  for (int c = 0; c < NCH; ++c) {
    gemm_gx<<<dim3(64, 16, 2), dim3(256), 0, stream>>>(
        e, wihf1, wihb1, b_f1, b_b1, gxc, len, c * CH, 256);
    lstm_scan<<<dim3(256), dim3(128), 0, stream>>>(
        gxc, whhf1, whhb1, len, out1, nullptr, hbuf, cbuf, bar, c * CH, g0);
    g0 += (c == 0) ? CH : CH - 1;
  }
  // layer 2 (+ chunked classifier)
  for (int c = 0; c < NCH; ++c) {
    gemm_gx<<<dim3(64, 16, 2), dim3(256), 0, stream>>>(
        out1, wihf2, wihb2, b_f2, b_b2, gxc, len, c * CH, 1024);
    lstm_scan<<<dim3(256), dim3(128), 0, stream>>>(
        gxc, whhf2, whhb2, len, nullptr, out2c, hbuf, cbuf, bar, c * CH, g0);
    g0 += (c == 0) ? CH : CH - 1;
    gemm_cls<<<dim3(64, 1, 2), dim3(256), 0, stream>>>(
        out2c, wcls, (float*)d_out, len, c * CH);
  }
}

// Round 5
// 8251.447 us; speedup vs baseline: 2.8439x; 1.3893x over previous
//
#include <hip/hip_runtime.h>

// BiLSTMTagger on MI355X (gfx950) — 256 MB workspace budget.
// Chunked pipeline (8 chunks x 64 steps per layer):
//   gemm_gx(chunk)  : gathered-A GEMM -> gx for chunk, both dirs (bwd pre-gathered)
//   lstm_scan(chunk): persistent 256-block scan, W_hh register/AGPR-resident.
//     Synchronization is DATA-FLOW TAGS, not a grid barrier: the only coupling
//     is within a 32-wave group (dir x 16-batch block); each producer wave
//     publishes a monotone tag after its h stores drain to LLC; consumers
//     poll their group's 32 tags (1 coalesced load + ballot). No atomic RMW.
//     WAR safety of the h ping-pong: tag>=s from wave W means W finished
//     iteration s-1, i.e. W already CONSUMED h[s-1]; so overwriting slot
//     (s+1)&1 == (s-1)&1 is safe once all tags >= s.
//   layer2: scan emits step-indexed chunk buffer; classifier = two separable
//           K=512 partial GEMMs accumulating into bias-initialized d_out.
// fp16 storage/MFMA, fp32 cell math.

typedef unsigned short u16;
typedef unsigned long long u64;
typedef _Float16 f16;
typedef __attribute__((ext_vector_type(8))) _Float16 f16x8;
typedef __attribute__((ext_vector_type(4))) float f32x4;

#define TT 512
#define HH 512
#define CH 64          // steps per chunk
#define NCH 8          // chunks

__device__ __forceinline__ u16 f2h(float f) { f16 h = (f16)f; return __builtin_bit_cast(u16, h); }
__device__ __forceinline__ float h2f(u16 s) { return (float)__builtin_bit_cast(f16, s); }
__device__ __forceinline__ float sigf(float x) { return 1.f / (1.f + __expf(-x)); }
__device__ __forceinline__ float tanhf_(float x) { return 1.f - 2.f / (__expf(2.f * x) + 1.f); }
__device__ __forceinline__ f32x4 zf4() { f32x4 z; z[0]=0.f; z[1]=0.f; z[2]=0.f; z[3]=0.f; return z; }

// LLC-coherent transport (agent scope = sc1, bypasses non-coherent per-XCD L2).
__device__ __forceinline__ void store_h(u16* p, u16 v) {
  __hip_atomic_store(p, v, __ATOMIC_RELAXED, __HIP_MEMORY_SCOPE_AGENT);
}
__device__ __forceinline__ f16x8 load_h16(const u16* p) {
  union { u64 q[2]; f16x8 v; } u;
  u.q[0] = __hip_atomic_load((const u64*)p,     __ATOMIC_RELAXED, __HIP_MEMORY_SCOPE_AGENT);
  u.q[1] = __hip_atomic_load((const u64*)p + 1, __ATOMIC_RELAXED, __HIP_MEMORY_SCOPE_AGENT);
  return u.v;
}
__device__ __forceinline__ void store_tag(int* p, int v) {
  __hip_atomic_store(p, v, __ATOMIC_RELAXED, __HIP_MEMORY_SCOPE_AGENT);
}
__device__ __forceinline__ int load_tag(const int* p) {
  return __hip_atomic_load(p, __ATOMIC_RELAXED, __HIP_MEMORY_SCOPE_AGENT);
}

// ---------------- utility kernels ----------------

struct CvtJob { const float* s; u16* d; int n; };
struct CvtJobs { CvtJob j[9]; };

__global__ void cvt_many(CvtJobs jobs) {
  CvtJob jb = jobs.j[blockIdx.y];
  int i = blockIdx.x * 256 + threadIdx.x;
  if (i < jb.n) jb.d[i] = f2h(jb.s[i]);
}

__global__ void embed_cast(const int* __restrict__ x, const float* __restrict__ emb,
                           u16* __restrict__ e) {
  int row = blockIdx.x;                 // b*T+t
  int tok = x[row];
  e[(size_t)row * 256 + threadIdx.x] = f2h(emb[(size_t)tok * 256 + threadIdx.x]);
}

__global__ void bias_init(float* __restrict__ o, const float* __restrict__ b, int n) {
  int i = blockIdx.x * 256 + threadIdx.x;
  if (i < n) o[i] = b[i & 63];
}

__global__ void fill_diag(float* __restrict__ o, int n, float sentinel) {
  int i = blockIdx.x * 256 + threadIdx.x;
  if (i < n) o[i] = (i == 0) ? sentinel : 0.f;
}

// ---------------- persistent BiLSTM scan, one chunk ----------------
// grid 256 x 128 thr (2 independent waves/block — no __syncthreads at all).
// Wave = one unit-tile: 16 batches x 16 units x 4 gates.
// Group = dir*8 + batch-group: 32 waves exchanging h through LLC.
// tags[group*32 + u_tile]: monotone; value v means "h[v-1+tagbase'] published".

__global__ __launch_bounds__(128, 1) void lstm_scan(
    const u16* __restrict__ gxc, const u16* __restrict__ whh_f,
    const u16* __restrict__ whh_b, const int* __restrict__ len,
    u16* __restrict__ out_pos, u16* __restrict__ out_chunk,
    u16* __restrict__ hbuf, float* __restrict__ cbuf, int* __restrict__ tags,
    int s0, int tagbase)
{
  const int bi = blockIdx.x;
  const int dir = bi >> 7;
  const int sub = bi & 127;
  const int b_base = (sub >> 4) * 16;
  const int u_tile = (sub & 15) * 2 + (threadIdx.x >> 6);   // 0..31 within group
  const int u_base = u_tile * 16;
  const int grp = dir * 8 + (sub >> 4);
  const int lane = threadIdx.x & 63;
  const int m16 = lane & 15, quad = lane >> 4;
  const u16* gxd = gxc + (size_t)dir * 8192 * 2048;
  const u16* whh = dir ? whh_b : whh_f;
  u16* hbd = hbuf + (size_t)dir * 2 * (128 * HH);
  int* gtags = tags + grp * 32;
  int* mytag = gtags + u_tile;

  // W_hh fragments: B[n=lane&15][k=quad*8+j], rows g*512 + u_base + n.
  // 64 f16x8 = 256 regs -> AGPRs (gfx950 unified file).
  f16x8 bf[4][16];
#pragma unroll
  for (int g = 0; g < 4; ++g) {
    const u16* wrow = whh + (size_t)(g * HH + u_base + m16) * HH + quad * 8;
#pragma unroll
    for (int ks = 0; ks < 16; ++ks)
      bf[g][ks] = *(const f16x8*)(wrow + ks * 32);
  }

  int lenr[4];
#pragma unroll
  for (int r = 0; r < 4; ++r) lenr[r] = len[b_base + quad * 4 + r];

  float cst[4];
  if (s0 == 0) {
#pragma unroll
    for (int r = 0; r < 4; ++r) {
      cst[r] = 0.f;
      store_h(&hbd[(b_base + quad * 4 + r) * HH + u_base + m16], 0);
    }
    asm volatile("s_waitcnt vmcnt(0)" ::: "memory");
    if (lane == 0) store_tag(mytag, tagbase + 1);       // h[0] published
  } else {
#pragma unroll
    for (int r = 0; r < 4; ++r)
      cst[r] = cbuf[(size_t)dir * 65536 + (b_base + quad * 4 + r) * HH + u_base + m16];
  }

  for (int i = 0; i < CH; ++i) {
    const int s = s0 + i;
    const u16* cur = hbd + (s & 1) * (128 * HH);
    u16* nxt = hbd + ((s + 1) & 1) * (128 * HH);

    // issue gx loads for this step BEFORE the poll (latency hides under it)
    u16 gpre[4][4];
#pragma unroll
    for (int r = 0; r < 4; ++r) {
      const int batch = b_base + quad * 4 + r;
      const u16* gq = gxd + (size_t)(batch * CH + i) * 2048 + u_base + m16;
      gpre[r][0] = gq[0]; gpre[r][1] = gq[512];
      gpre[r][2] = gq[1024]; gpre[r][3] = gq[1536];
    }

    // wait until all 32 producer waves of this group published h[s]
    const int want = tagbase + s + 1;
    while (true) {
      int t = load_tag(gtags + (lane & 31));
      if (__ballot(t < want) == 0ull) break;
      __builtin_amdgcn_s_sleep(1);
    }

    f32x4 a0 = zf4(), a1 = zf4(), a2 = zf4(), a3 = zf4();
    const u16* arow = cur + (b_base + m16) * HH + quad * 8;   // A[m=lane&15][k]
#pragma unroll
    for (int ks = 0; ks < 16; ++ks) {
      f16x8 a = load_h16(arow + ks * 32);
      a0 = __builtin_amdgcn_mfma_f32_16x16x32_f16(a, bf[0][ks], a0, 0, 0, 0);
      a1 = __builtin_amdgcn_mfma_f32_16x16x32_f16(a, bf[1][ks], a1, 0, 0, 0);
      a2 = __builtin_amdgcn_mfma_f32_16x16x32_f16(a, bf[2][ks], a2, 0, 0, 0);
      a3 = __builtin_amdgcn_mfma_f32_16x16x32_f16(a, bf[3][ks], a3, 0, 0, 0);
    }
#pragma unroll
    for (int r = 0; r < 4; ++r) {
      const int batch = b_base + quad * 4 + r;    // C/D row = quad*4+reg
      const int L = lenr[r];
      const bool valid = s < L;
      float gi = a0[r] + h2f(gpre[r][0]);
      float gf = a1[r] + h2f(gpre[r][1]);
      float gg = a2[r] + h2f(gpre[r][2]);
      float go = a3[r] + h2f(gpre[r][3]);
      float c = sigf(gf) * cst[r] + sigf(gi) * tanhf_(gg);
      cst[r] = c;
      float h = sigf(go) * tanhf_(c);
      u16 hv = f2h(h);
      store_h(&nxt[batch * HH + u_base + m16], hv);
      if (out_pos) {
        const int p = dir ? (L - 1 - s) : s;
        const int wrow = valid ? (p < 0 ? 0 : p) : s;
        out_pos[(size_t)(batch * TT + wrow) * 1024 + dir * 512 + u_base + m16]
            = valid ? hv : (u16)0;
      } else {
        out_chunk[(size_t)(batch * CH + i) * 1024 + dir * 512 + u_base + m16] = hv;
      }
    }
    asm volatile("s_waitcnt vmcnt(0)" ::: "memory");    // h[s+1] at LLC
    if (lane == 0) store_tag(mytag, want + 1);          // publish h[s+1]
  }

#pragma unroll
  for (int r = 0; r < 4; ++r)
    cbuf[(size_t)dir * 65536 + (b_base + quad * 4 + r) * HH + u_base + m16] = cst[r];
}

// ---------------- gx GEMM (gathered A rows): gxc[dir][m][n] = A[row(m)] @ B[n]^T + bias
// M=8192 (b*64+i), N=2048, K in {256,1024}. fwd row = b*T+s ; bwd row = b*T+clamp(L-1-s).

__global__ __launch_bounds__(256) void gemm_gx(
    const u16* __restrict__ A, const u16* __restrict__ Bf, const u16* __restrict__ Bb,
    const float* __restrict__ biasf, const float* __restrict__ biasb,
    u16* __restrict__ gxc, const int* __restrict__ len, int s0, int K)
{
  const int dir = blockIdx.z;
  const u16* Bm = dir ? Bb : Bf;
  const float* bias = dir ? biasb : biasf;
  u16* Cp = gxc + (size_t)dir * 8192 * 2048;
  __shared__ u16 As[128 * 40];
  __shared__ u16 Bs[128 * 40];
  const int tid = threadIdx.x;
  const int lane = tid & 63;
  const int wv = tid >> 6;
  const int wr = (wv >> 1) * 64, wc = (wv & 1) * 64;
  const int m16 = lane & 15, quad = lane >> 4;
  const int rowst = tid >> 1;
  const int offst = (tid & 1) * 16;
  const int m0 = blockIdx.x * 128;
  const int n0 = blockIdx.y * 128;

  const int m = m0 + rowst;
  const int b = m >> 6, i = m & 63, s = s0 + i;
  int pos;
  if (dir) { int p = len[b] - 1 - s; pos = p < 0 ? 0 : p; } else { pos = s; }
  const u16* Arow = A + ((size_t)b * TT + pos) * K;
  const u16* Brow = Bm + (size_t)(n0 + rowst) * K;

  f32x4 acc[4][4];
#pragma unroll
  for (int a = 0; a < 4; ++a)
#pragma unroll
    for (int c = 0; c < 4; ++c) acc[a][c] = zf4();

  for (int kt = 0; kt < K; kt += 32) {
    *(uint4*)&As[rowst * 40 + offst]     = *(const uint4*)(Arow + kt + offst);
    *(uint4*)&As[rowst * 40 + offst + 8] = *(const uint4*)(Arow + kt + offst + 8);
    *(uint4*)&Bs[rowst * 40 + offst]     = *(const uint4*)(Brow + kt + offst);
    *(uint4*)&Bs[rowst * 40 + offst + 8] = *(const uint4*)(Brow + kt + offst + 8);
    __syncthreads();
    f16x8 af[4], bfr[4];
#pragma unroll
    for (int mt = 0; mt < 4; ++mt)
      af[mt] = *(const f16x8*)&As[(wr + mt * 16 + m16) * 40 + quad * 8];
#pragma unroll
    for (int nt = 0; nt < 4; ++nt)
      bfr[nt] = *(const f16x8*)&Bs[(wc + nt * 16 + m16) * 40 + quad * 8];
#pragma unroll
    for (int mt = 0; mt < 4; ++mt)
#pragma unroll
      for (int nt = 0; nt < 4; ++nt)
        acc[mt][nt] = __builtin_amdgcn_mfma_f32_16x16x32_f16(af[mt], bfr[nt], acc[mt][nt], 0, 0, 0);
    __syncthreads();
  }

#pragma unroll
  for (int mt = 0; mt < 4; ++mt)
#pragma unroll
    for (int nt = 0; nt < 4; ++nt) {
      const int n = n0 + wc + nt * 16 + m16;
      const float bv = bias[n];
#pragma unroll
      for (int r = 0; r < 4; ++r) {
        const int mm = m0 + wr + mt * 16 + quad * 4 + r;
        Cp[(size_t)mm * 2048 + n] = f2h(acc[mt][nt][r] + bv);
      }
    }
}

// ---------------- classifier partial GEMM (K=512 half), accumulate into d_out

__global__ __launch_bounds__(256) void gemm_cls(
    const u16* __restrict__ out2c, const u16* __restrict__ wcls,
    float* __restrict__ dout, const int* __restrict__ len, int s0)
{
  const int dir = blockIdx.z;
  __shared__ u16 As[128 * 40];
  __shared__ u16 Bs[128 * 40];
  const int tid = threadIdx.x;
  const int lane = tid & 63;
  const int wv = tid >> 6;
  const int wr = (wv >> 1) * 64, wc = (wv & 1) * 64;
  const int m16 = lane & 15, quad = lane >> 4;
  const int rowst = tid >> 1;
  const int offst = (tid & 1) * 16;
  const int m0 = blockIdx.x * 128;
  const u16* Arow = out2c + (size_t)(m0 + rowst) * 1024 + dir * 512;
  const int rowb = rowst < 64 ? rowst : 63;
  const u16* Brow = wcls + (size_t)rowb * 1024 + dir * 512;

  f32x4 acc[4][4];
#pragma unroll
  for (int a = 0; a < 4; ++a)
#pragma unroll
    for (int c = 0; c < 4; ++c) acc[a][c] = zf4();

  for (int kt = 0; kt < 512; kt += 32) {
    *(uint4*)&As[rowst * 40 + offst]     = *(const uint4*)(Arow + kt + offst);
    *(uint4*)&As[rowst * 40 + offst + 8] = *(const uint4*)(Arow + kt + offst + 8);
    *(uint4*)&Bs[rowst * 40 + offst]     = *(const uint4*)(Brow + kt + offst);
    *(uint4*)&Bs[rowst * 40 + offst + 8] = *(const uint4*)(Brow + kt + offst + 8);
    __syncthreads();
    f16x8 af[4], bfr[4];
#pragma unroll
    for (int mt = 0; mt < 4; ++mt)
      af[mt] = *(const f16x8*)&As[(wr + mt * 16 + m16) * 40 + quad * 8];
#pragma unroll
    for (int nt = 0; nt < 4; ++nt)
      bfr[nt] = *(const f16x8*)&Bs[(wc + nt * 16 + m16) * 40 + quad * 8];
#pragma unroll
    for (int mt = 0; mt < 4; ++mt)
#pragma unroll
      for (int nt = 0; nt < 4; ++nt)
        acc[mt][nt] = __builtin_amdgcn_mfma_f32_16x16x32_f16(af[mt], bfr[nt], acc[mt][nt], 0, 0, 0);
    __syncthreads();
  }

#pragma unroll
  for (int mt = 0; mt < 4; ++mt)
#pragma unroll
    for (int nt = 0; nt < 4; ++nt) {
      const int n = wc + nt * 16 + m16;
      if (n < 64) {
#pragma unroll
        for (int r = 0; r < 4; ++r) {
          const int m = m0 + wr + mt * 16 + quad * 4 + r;
          const int b = m >> 6, i = m & 63, s = s0 + i;
          const int L = len[b];
          if (s < L) {
            const int pos = dir ? (L - 1 - s) : s;
            atomicAdd(&dout[((size_t)b * TT + pos) * 64 + n], acc[mt][nt][r]);
          }
        }
      }
    }
}

// ---------------- launch ----------------

extern "C" void kernel_launch(void* const* d_in, const int* in_sizes, int n_in,
                              void* d_out, int out_size, void* d_ws, size_t ws_size,
                              hipStream_t stream) {
  const int*   x      = (const int*)d_in[0];
  const int*   len    = (const int*)d_in[1];
  const float* emb    = (const float*)d_in[2];
  const float* Wih_f1 = (const float*)d_in[3];
  const float* Whh_f1 = (const float*)d_in[4];
  const float* b_f1   = (const float*)d_in[5];
  const float* Wih_b1 = (const float*)d_in[6];
  const float* Whh_b1 = (const float*)d_in[7];
  const float* b_b1   = (const float*)d_in[8];
  const float* Wih_f2 = (const float*)d_in[9];
  const float* Whh_f2 = (const float*)d_in[10];
  const float* b_f2   = (const float*)d_in[11];
  const float* Wih_b2 = (const float*)d_in[12];
  const float* Whh_b2 = (const float*)d_in[13];
  const float* b_b2   = (const float*)d_in[14];
  const float* W_cls  = (const float*)d_in[15];
  const float* b_cls  = (const float*)d_in[16];

  const size_t GXC  = (size_t)2 * 8192 * 2048 * 2;     // 64 MB
  const size_t OUT1 = (size_t)65536 * 1024 * 2;        // 128 MB
  const size_t EREG = (size_t)65536 * 256 * 2;         // 32 MB (also out2 chunk 16 MB)
  const size_t WTS  = (size_t)9502720 * 2;             // 18.1 MB
  const size_t NEED = GXC + OUT1 + EREG + WTS + 524288 + 524288 + 4096;
  if (ws_size < NEED) {
    fill_diag<<<dim3((out_size + 255) / 256), dim3(256), 0, stream>>>(
        (float*)d_out, out_size, (float)(ws_size >> 20));
    return;
  }

  char* w = (char*)d_ws;
  u16* gxc   = (u16*)w; w += GXC;
  u16* out1  = (u16*)w; w += OUT1;
  u16* ereg  = (u16*)w; w += EREG;     // e (layer1) -> out2 chunk (layer2)
  u16* wihf1 = (u16*)w; w += (size_t)2048 * 256 * 2;
  u16* wihb1 = (u16*)w; w += (size_t)2048 * 256 * 2;
  u16* whhf1 = (u16*)w; w += (size_t)2048 * 512 * 2;
  u16* whhb1 = (u16*)w; w += (size_t)2048 * 512 * 2;
  u16* wihf2 = (u16*)w; w += (size_t)2048 * 1024 * 2;
  u16* wihb2 = (u16*)w; w += (size_t)2048 * 1024 * 2;
  u16* whhf2 = (u16*)w; w += (size_t)2048 * 512 * 2;
  u16* whhb2 = (u16*)w; w += (size_t)2048 * 512 * 2;
  u16* wcls  = (u16*)w; w += (size_t)64 * 1024 * 2;
  u16* hbuf  = (u16*)w; w += 524288;
  float* cbuf = (float*)w; w += 524288;
  int* tags  = (int*)w; w += 4096;

  u16* e     = ereg;
  u16* out2c = ereg;   // 16 MB, live only in layer 2

  CvtJobs jobs = {{
    { Wih_f1, wihf1, 2048 * 256 }, { Wih_b1, wihb1, 2048 * 256 },
    { Whh_f1, whhf1, 2048 * 512 }, { Whh_b1, whhb1, 2048 * 512 },
    { Wih_f2, wihf2, 2048 * 1024 }, { Wih_b2, wihb2, 2048 * 1024 },
    { Whh_f2, whhf2, 2048 * 512 }, { Whh_b2, whhb2, 2048 * 512 },
    { W_cls,  wcls,  64 * 1024 },
  }};
  cvt_many<<<dim3(8192, 9), dim3(256), 0, stream>>>(jobs);
  embed_cast<<<dim3(65536), dim3(256), 0, stream>>>(x, emb, e);
  bias_init<<<dim3(16384), dim3(256), 0, stream>>>((float*)d_out, b_cls, 65536 * 64);
  hipMemsetAsync(tags, 0, 4096, stream);

  // layer 1 (tagbase 0: init publishes 1, step s publishes s+2, max 513)
  for (int c = 0; c < NCH; ++c) {
    gemm_gx<<<dim3(64, 16, 2), dim3(256), 0, stream>>>(
        e, wihf1, wihb1, b_f1, b_b1, gxc, len, c * CH, 256);
    lstm_scan<<<dim3(256), dim3(128), 0, stream>>>(
        gxc, whhf1, whhb1, len, out1, nullptr, hbuf, cbuf, tags, c * CH, 0);
  }
  // layer 2 (tagbase 513 > 513-max of layer 1 tags? init publishes 514) + classifier
  for (int c = 0; c < NCH; ++c) {
    gemm_gx<<<dim3(64, 16, 2), dim3(256), 0, stream>>>(
        out1, wihf2, wihb2, b_f2, b_b2, gxc, len, c * CH, 1024);
    lstm_scan<<<dim3(256), dim3(128), 0, stream>>>(
        gxc, whhf2, whhb2, len, nullptr, out2c, hbuf, cbuf, tags, c * CH, 513);
    gemm_cls<<<dim3(64, 1, 2), dim3(256), 0, stream>>>(
        out2c, wcls, (float*)d_out, len, c * CH);
  }
}

// Round 6
// 8055.492 us; speedup vs baseline: 2.9131x; 1.0243x over previous
//
#include <hip/hip_runtime.h>

// BiLSTMTagger on MI355X (gfx950) — 256 MB workspace budget.
// Chunked pipeline (8 chunks x 64 steps per layer):
//   gemm_gx(chunk)  : gathered-A GEMM -> gx for chunk, both dirs (bwd pre-gathered)
//   lstm_scan(chunk): persistent 256-block scan, W_hh register/AGPR-resident.
//     Sync = data-flow tags, one 64B LLC line PER TAG (no shared-line
//     contention); producers store their private tag after h drains to LLC;
//     consumers poll their group's 32 tags with a 32-lane gather + ballot.
//     No atomic RMW anywhere. WAR safety of the h ping-pong: tag>=s from wave
//     W means W finished step s-1, i.e. already consumed h[s-1]; overwriting
//     slot (s+1)&1 == (s-1)&1 is therefore safe once all tags >= s.
//   layer2: scan emits step-indexed chunk buffer; classifier = two separable
//           K=512 partial GEMMs accumulating into bias-initialized d_out.
// fp16 storage/MFMA, fp32 cell math.

typedef unsigned short u16;
typedef unsigned long long u64;
typedef _Float16 f16;
typedef __attribute__((ext_vector_type(8))) _Float16 f16x8;
typedef __attribute__((ext_vector_type(4))) float f32x4;

#define TT 512
#define HH 512
#define CH 64          // steps per chunk
#define NCH 8          // chunks
#define TSTR 16        // tag stride in ints: 64B = one LLC line per tag

__device__ __forceinline__ u16 f2h(float f) { f16 h = (f16)f; return __builtin_bit_cast(u16, h); }
__device__ __forceinline__ float h2f(u16 s) { return (float)__builtin_bit_cast(f16, s); }
__device__ __forceinline__ float sigf(float x) { return 1.f / (1.f + __expf(-x)); }
__device__ __forceinline__ float tanhf_(float x) { return 1.f - 2.f / (__expf(2.f * x) + 1.f); }
__device__ __forceinline__ f32x4 zf4() { f32x4 z; z[0]=0.f; z[1]=0.f; z[2]=0.f; z[3]=0.f; return z; }

// LLC-coherent transport (agent scope = sc1, bypasses non-coherent per-XCD L2).
__device__ __forceinline__ void store_h(u16* p, u16 v) {
  __hip_atomic_store(p, v, __ATOMIC_RELAXED, __HIP_MEMORY_SCOPE_AGENT);
}
__device__ __forceinline__ f16x8 load_h16(const u16* p) {
  union { u64 q[2]; f16x8 v; } u;
  u.q[0] = __hip_atomic_load((const u64*)p,     __ATOMIC_RELAXED, __HIP_MEMORY_SCOPE_AGENT);
  u.q[1] = __hip_atomic_load((const u64*)p + 1, __ATOMIC_RELAXED, __HIP_MEMORY_SCOPE_AGENT);
  return u.v;
}
__device__ __forceinline__ void store_tag(int* p, int v) {
  __hip_atomic_store(p, v, __ATOMIC_RELAXED, __HIP_MEMORY_SCOPE_AGENT);
}
__device__ __forceinline__ int load_tag(const int* p) {
  return __hip_atomic_load(p, __ATOMIC_RELAXED, __HIP_MEMORY_SCOPE_AGENT);
}

// ---------------- utility kernels ----------------

struct CvtJob { const float* s; u16* d; int n; };
struct CvtJobs { CvtJob j[9]; };

__global__ void cvt_many(CvtJobs jobs) {
  CvtJob jb = jobs.j[blockIdx.y];
  int i = blockIdx.x * 256 + threadIdx.x;
  if (i < jb.n) jb.d[i] = f2h(jb.s[i]);
}

__global__ void embed_cast(const int* __restrict__ x, const float* __restrict__ emb,
                           u16* __restrict__ e) {
  int row = blockIdx.x;                 // b*T+t
  int tok = x[row];
  e[(size_t)row * 256 + threadIdx.x] = f2h(emb[(size_t)tok * 256 + threadIdx.x]);
}

__global__ void bias_init(float* __restrict__ o, const float* __restrict__ b, int n) {
  int i = blockIdx.x * 256 + threadIdx.x;
  if (i < n) o[i] = b[i & 63];
}

__global__ void fill_diag(float* __restrict__ o, int n, float sentinel) {
  int i = blockIdx.x * 256 + threadIdx.x;
  if (i < n) o[i] = (i == 0) ? sentinel : 0.f;
}

// ---------------- persistent BiLSTM scan, one chunk ----------------
// grid 256 x 128 thr (2 independent waves/block — no __syncthreads at all).
// Wave = one unit-tile: 16 batches x 16 units x 4 gates.
// Group = dir*8 + batch-group: 32 waves exchanging h through LLC.
// tags[(grp*32+u)*TSTR]: monotone; value v means "h[v-1-ish] published".

__global__ __launch_bounds__(128, 1) void lstm_scan(
    const u16* __restrict__ gxc, const u16* __restrict__ whh_f,
    const u16* __restrict__ whh_b, const int* __restrict__ len,
    u16* __restrict__ out_pos, u16* __restrict__ out_chunk,
    u16* __restrict__ hbuf, float* __restrict__ cbuf, int* __restrict__ tags,
    int s0, int tagbase)
{
  const int bi = blockIdx.x;
  const int dir = bi >> 7;
  const int sub = bi & 127;
  const int b_base = (sub >> 4) * 16;
  const int u_tile = (sub & 15) * 2 + (threadIdx.x >> 6);   // 0..31 within group
  const int u_base = u_tile * 16;
  const int grp = dir * 8 + (sub >> 4);
  const int lane = threadIdx.x & 63;
  const int m16 = lane & 15, quad = lane >> 4;
  const u16* gxd = gxc + (size_t)dir * 8192 * 2048;
  const u16* whh = dir ? whh_b : whh_f;
  u16* hbd = hbuf + (size_t)dir * 2 * (128 * HH);
  int* gtags = tags + grp * 32 * TSTR;
  int* mytag = gtags + u_tile * TSTR;

  // W_hh fragments: B[n=lane&15][k=quad*8+j], rows g*512 + u_base + n.
  // 64 f16x8 = 256 regs -> AGPRs (gfx950 unified file).
  f16x8 bf[4][16];
#pragma unroll
  for (int g = 0; g < 4; ++g) {
    const u16* wrow = whh + (size_t)(g * HH + u_base + m16) * HH + quad * 8;
#pragma unroll
    for (int ks = 0; ks < 16; ++ks)
      bf[g][ks] = *(const f16x8*)(wrow + ks * 32);
  }

  int lenr[4];
#pragma unroll
  for (int r = 0; r < 4; ++r) lenr[r] = len[b_base + quad * 4 + r];

  float cst[4];
  if (s0 == 0) {
#pragma unroll
    for (int r = 0; r < 4; ++r) {
      cst[r] = 0.f;
      store_h(&hbd[(b_base + quad * 4 + r) * HH + u_base + m16], 0);
    }
    asm volatile("s_waitcnt vmcnt(0)" ::: "memory");
    if (lane == 0) store_tag(mytag, tagbase + 1);       // h[0] published
  } else {
#pragma unroll
    for (int r = 0; r < 4; ++r)
      cst[r] = cbuf[(size_t)dir * 65536 + (b_base + quad * 4 + r) * HH + u_base + m16];
  }

  for (int i = 0; i < CH; ++i) {
    const int s = s0 + i;
    const u16* cur = hbd + (s & 1) * (128 * HH);
    u16* nxt = hbd + ((s + 1) & 1) * (128 * HH);

    // issue gx loads for this step BEFORE the poll (latency hides under it)
    u16 gpre[4][4];
#pragma unroll
    for (int r = 0; r < 4; ++r) {
      const int batch = b_base + quad * 4 + r;
      const u16* gq = gxd + (size_t)(batch * CH + i) * 2048 + u_base + m16;
      gpre[r][0] = gq[0]; gpre[r][1] = gq[512];
      gpre[r][2] = gq[1024]; gpre[r][3] = gq[1536];
    }

    // wait until all 32 producer waves of this group published h[s].
    // 32-lane gather: each lane polls a DIFFERENT 64B line (no hot line).
    const int want = tagbase + s + 1;
    while (true) {
      int t = load_tag(gtags + (lane & 31) * TSTR);
      if (__ballot(t < want) == 0ull) break;
      __builtin_amdgcn_s_sleep(1);
    }

    f32x4 a0 = zf4(), a1 = zf4(), a2 = zf4(), a3 = zf4();
    const u16* arow = cur + (b_base + m16) * HH + quad * 8;   // A[m=lane&15][k]
#pragma unroll
    for (int ks = 0; ks < 16; ++ks) {
      f16x8 a = load_h16(arow + ks * 32);
      a0 = __builtin_amdgcn_mfma_f32_16x16x32_f16(a, bf[0][ks], a0, 0, 0, 0);
      a1 = __builtin_amdgcn_mfma_f32_16x16x32_f16(a, bf[1][ks], a1, 0, 0, 0);
      a2 = __builtin_amdgcn_mfma_f32_16x16x32_f16(a, bf[2][ks], a2, 0, 0, 0);
      a3 = __builtin_amdgcn_mfma_f32_16x16x32_f16(a, bf[3][ks], a3, 0, 0, 0);
    }

    // cell math + h stores FIRST (publish path), out stores AFTER the tag so
    // the vmcnt(0) drain covers only the 8 tiny h stores.
    u16 hv[4];
#pragma unroll
    for (int r = 0; r < 4; ++r) {
      const int batch = b_base + quad * 4 + r;    // C/D row = quad*4+reg
      float gi = a0[r] + h2f(gpre[r][0]);
      float gf = a1[r] + h2f(gpre[r][1]);
      float gg = a2[r] + h2f(gpre[r][2]);
      float go = a3[r] + h2f(gpre[r][3]);
      float c = sigf(gf) * cst[r] + sigf(gi) * tanhf_(gg);
      cst[r] = c;
      float h = sigf(go) * tanhf_(c);
      hv[r] = f2h(h);
      store_h(&nxt[batch * HH + u_base + m16], hv[r]);
    }
    asm volatile("s_waitcnt vmcnt(0)" ::: "memory");    // h[s+1] at LLC
    if (lane == 0) store_tag(mytag, want + 1);          // publish h[s+1]

#pragma unroll
    for (int r = 0; r < 4; ++r) {
      const int batch = b_base + quad * 4 + r;
      const int L = lenr[r];
      const bool valid = s < L;
      if (out_pos) {
        const int p = dir ? (L - 1 - s) : s;
        const int wrow = valid ? (p < 0 ? 0 : p) : s;
        out_pos[(size_t)(batch * TT + wrow) * 1024 + dir * 512 + u_base + m16]
            = valid ? hv[r] : (u16)0;
      } else {
        out_chunk[(size_t)(batch * CH + i) * 1024 + dir * 512 + u_base + m16] = hv[r];
      }
    }
  }

#pragma unroll
  for (int r = 0; r < 4; ++r)
    cbuf[(size_t)dir * 65536 + (b_base + quad * 4 + r) * HH + u_base + m16] = cst[r];
}

// ---------------- gx GEMM (gathered A rows): gxc[dir][m][n] = A[row(m)] @ B[n]^T + bias
// M=8192 (b*64+i), N=2048, K in {256,1024}. fwd row = b*T+s ; bwd row = b*T+clamp(L-1-s).

__global__ __launch_bounds__(256) void gemm_gx(
    const u16* __restrict__ A, const u16* __restrict__ Bf, const u16* __restrict__ Bb,
    const float* __restrict__ biasf, const float* __restrict__ biasb,
    u16* __restrict__ gxc, const int* __restrict__ len, int s0, int K)
{
  const int dir = blockIdx.z;
  const u16* Bm = dir ? Bb : Bf;
  const float* bias = dir ? biasb : biasf;
  u16* Cp = gxc + (size_t)dir * 8192 * 2048;
  __shared__ u16 As[128 * 40];
  __shared__ u16 Bs[128 * 40];
  const int tid = threadIdx.x;
  const int lane = tid & 63;
  const int wv = tid >> 6;
  const int wr = (wv >> 1) * 64, wc = (wv & 1) * 64;
  const int m16 = lane & 15, quad = lane >> 4;
  const int rowst = tid >> 1;
  const int offst = (tid & 1) * 16;
  const int m0 = blockIdx.x * 128;
  const int n0 = blockIdx.y * 128;

  const int m = m0 + rowst;
  const int b = m >> 6, i = m & 63, s = s0 + i;
  int pos;
  if (dir) { int p = len[b] - 1 - s; pos = p < 0 ? 0 : p; } else { pos = s; }
  const u16* Arow = A + ((size_t)b * TT + pos) * K;
  const u16* Brow = Bm + (size_t)(n0 + rowst) * K;

  f32x4 acc[4][4];
#pragma unroll
  for (int a = 0; a < 4; ++a)
#pragma unroll
    for (int c = 0; c < 4; ++c) acc[a][c] = zf4();

  for (int kt = 0; kt < K; kt += 32) {
    *(uint4*)&As[rowst * 40 + offst]     = *(const uint4*)(Arow + kt + offst);
    *(uint4*)&As[rowst * 40 + offst + 8] = *(const uint4*)(Arow + kt + offst + 8);
    *(uint4*)&Bs[rowst * 40 + offst]     = *(const uint4*)(Brow + kt + offst);
    *(uint4*)&Bs[rowst * 40 + offst + 8] = *(const uint4*)(Brow + kt + offst + 8);
    __syncthreads();
    f16x8 af[4], bfr[4];
#pragma unroll
    for (int mt = 0; mt < 4; ++mt)
      af[mt] = *(const f16x8*)&As[(wr + mt * 16 + m16) * 40 + quad * 8];
#pragma unroll
    for (int nt = 0; nt < 4; ++nt)
      bfr[nt] = *(const f16x8*)&Bs[(wc + nt * 16 + m16) * 40 + quad * 8];
#pragma unroll
    for (int mt = 0; mt < 4; ++mt)
#pragma unroll
      for (int nt = 0; nt < 4; ++nt)
        acc[mt][nt] = __builtin_amdgcn_mfma_f32_16x16x32_f16(af[mt], bfr[nt], acc[mt][nt], 0, 0, 0);
    __syncthreads();
  }

#pragma unroll
  for (int mt = 0; mt < 4; ++mt)
#pragma unroll
    for (int nt = 0; nt < 4; ++nt) {
      const int n = n0 + wc + nt * 16 + m16;
      const float bv = bias[n];
#pragma unroll
      for (int r = 0; r < 4; ++r) {
        const int mm = m0 + wr + mt * 16 + quad * 4 + r;
        Cp[(size_t)mm * 2048 + n] = f2h(acc[mt][nt][r] + bv);
      }
    }
}

// ---------------- classifier partial GEMM (K=512 half), accumulate into d_out

__global__ __launch_bounds__(256) void gemm_cls(
    const u16* __restrict__ out2c, const u16* __restrict__ wcls,
    float* __restrict__ dout, const int* __restrict__ len, int s0)
{
  const int dir = blockIdx.z;
  __shared__ u16 As[128 * 40];
  __shared__ u16 Bs[128 * 40];
  const int tid = threadIdx.x;
  const int lane = tid & 63;
  const int wv = tid >> 6;
  const int wr = (wv >> 1) * 64, wc = (wv & 1) * 64;
  const int m16 = lane & 15, quad = lane >> 4;
  const int rowst = tid >> 1;
  const int offst = (tid & 1) * 16;
  const int m0 = blockIdx.x * 128;
  const u16* Arow = out2c + (size_t)(m0 + rowst) * 1024 + dir * 512;
  const int rowb = rowst < 64 ? rowst : 63;
  const u16* Brow = wcls + (size_t)rowb * 1024 + dir * 512;

  f32x4 acc[4][4];
#pragma unroll
  for (int a = 0; a < 4; ++a)
#pragma unroll
    for (int c = 0; c < 4; ++c) acc[a][c] = zf4();

  for (int kt = 0; kt < 512; kt += 32) {
    *(uint4*)&As[rowst * 40 + offst]     = *(const uint4*)(Arow + kt + offst);
    *(uint4*)&As[rowst * 40 + offst + 8] = *(const uint4*)(Arow + kt + offst + 8);
    *(uint4*)&Bs[rowst * 40 + offst]     = *(const uint4*)(Brow + kt + offst);
    *(uint4*)&Bs[rowst * 40 + offst + 8] = *(const uint4*)(Brow + kt + offst + 8);
    __syncthreads();
    f16x8 af[4], bfr[4];
#pragma unroll
    for (int mt = 0; mt < 4; ++mt)
      af[mt] = *(const f16x8*)&As[(wr + mt * 16 + m16) * 40 + quad * 8];
#pragma unroll
    for (int nt = 0; nt < 4; ++nt)
      bfr[nt] = *(const f16x8*)&Bs[(wc + nt * 16 + m16) * 40 + quad * 8];
#pragma unroll
    for (int mt = 0; mt < 4; ++mt)
#pragma unroll
      for (int nt = 0; nt < 4; ++nt)
        acc[mt][nt] = __builtin_amdgcn_mfma_f32_16x16x32_f16(af[mt], bfr[nt], acc[mt][nt], 0, 0, 0);
    __syncthreads();
  }

#pragma unroll
  for (int mt = 0; mt < 4; ++mt)
#pragma unroll
    for (int nt = 0; nt < 4; ++nt) {
      const int n = wc + nt * 16 + m16;
      if (n < 64) {
#pragma unroll
        for (int r = 0; r < 4; ++r) {
          const int m = m0 + wr + mt * 16 + quad * 4 + r;
          const int b = m >> 6, i = m & 63, s = s0 + i;
          const int L = len[b];
          if (s < L) {
            const int pos = dir ? (L - 1 - s) : s;
            atomicAdd(&dout[((size_t)b * TT + pos) * 64 + n], acc[mt][nt][r]);
          }
        }
      }
    }
}

// ---------------- launch ----------------

extern "C" void kernel_launch(void* const* d_in, const int* in_sizes, int n_in,
                              void* d_out, int out_size, void* d_ws, size_t ws_size,
                              hipStream_t stream) {
  const int*   x      = (const int*)d_in[0];
  const int*   len    = (const int*)d_in[1];
  const float* emb    = (const float*)d_in[2];
  const float* Wih_f1 = (const float*)d_in[3];
  const float* Whh_f1 = (const float*)d_in[4];
  const float* b_f1   = (const float*)d_in[5];
  const float* Wih_b1 = (const float*)d_in[6];
  const float* Whh_b1 = (const float*)d_in[7];
  const float* b_b1   = (const float*)d_in[8];
  const float* Wih_f2 = (const float*)d_in[9];
  const float* Whh_f2 = (const float*)d_in[10];
  const float* b_f2   = (const float*)d_in[11];
  const float* Wih_b2 = (const float*)d_in[12];
  const float* Whh_b2 = (const float*)d_in[13];
  const float* b_b2   = (const float*)d_in[14];
  const float* W_cls  = (const float*)d_in[15];
  const float* b_cls  = (const float*)d_in[16];

  const size_t GXC  = (size_t)2 * 8192 * 2048 * 2;     // 64 MB
  const size_t OUT1 = (size_t)65536 * 1024 * 2;        // 128 MB
  const size_t EREG = (size_t)65536 * 256 * 2;         // 32 MB (also out2 chunk 16 MB)
  const size_t WTS  = (size_t)9502720 * 2;             // 18.1 MB
  const size_t TAGS = 32768;                           // 16 grp x 32 x 64B
  const size_t NEED = GXC + OUT1 + EREG + WTS + 524288 + 524288 + TAGS;
  if (ws_size < NEED) {
    fill_diag<<<dim3((out_size + 255) / 256), dim3(256), 0, stream>>>(
        (float*)d_out, out_size, (float)(ws_size >> 20));
    return;
  }

  char* w = (char*)d_ws;
  u16* gxc   = (u16*)w; w += GXC;
  u16* out1  = (u16*)w; w += OUT1;
  u16* ereg  = (u16*)w; w += EREG;     // e (layer1) -> out2 chunk (layer2)
  u16* wihf1 = (u16*)w; w += (size_t)2048 * 256 * 2;
  u16* wihb1 = (u16*)w; w += (size_t)2048 * 256 * 2;
  u16* whhf1 = (u16*)w; w += (size_t)2048 * 512 * 2;
  u16* whhb1 = (u16*)w; w += (size_t)2048 * 512 * 2;
  u16* wihf2 = (u16*)w; w += (size_t)2048 * 1024 * 2;
  u16* wihb2 = (u16*)w; w += (size_t)2048 * 1024 * 2;
  u16* whhf2 = (u16*)w; w += (size_t)2048 * 512 * 2;
  u16* whhb2 = (u16*)w; w += (size_t)2048 * 512 * 2;
  u16* wcls  = (u16*)w; w += (size_t)64 * 1024 * 2;
  u16* hbuf  = (u16*)w; w += 524288;
  float* cbuf = (float*)w; w += 524288;
  int* tags  = (int*)w; w += TAGS;

  u16* e     = ereg;
  u16* out2c = ereg;   // 16 MB, live only in layer 2

  CvtJobs jobs = {{
    { Wih_f1, wihf1, 2048 * 256 }, { Wih_b1, wihb1, 2048 * 256 },
    { Whh_f1, whhf1, 2048 * 512 }, { Whh_b1, whhb1, 2048 * 512 },
    { Wih_f2, wihf2, 2048 * 1024 }, { Wih_b2, wihb2, 2048 * 1024 },
    { Whh_f2, whhf2, 2048 * 512 }, { Whh_b2, whhb2, 2048 * 512 },
    { W_cls,  wcls,  64 * 1024 },
  }};
  cvt_many<<<dim3(8192, 9), dim3(256), 0, stream>>>(jobs);
  embed_cast<<<dim3(65536), dim3(256), 0, stream>>>(x, emb, e);
  bias_init<<<dim3(16384), dim3(256), 0, stream>>>((float*)d_out, b_cls, 65536 * 64);
  hipMemsetAsync(tags, 0, TAGS, stream);

  // layer 1 (tagbase 0: init publishes 1, step s publishes s+2, max 513)
  for (int c = 0; c < NCH; ++c) {
    gemm_gx<<<dim3(64, 16, 2), dim3(256), 0, stream>>>(
        e, wihf1, wihb1, b_f1, b_b1, gxc, len, c * CH, 256);
    lstm_scan<<<dim3(256), dim3(128), 0, stream>>>(
        gxc, whhf1, whhb1, len, out1, nullptr, hbuf, cbuf, tags, c * CH, 0);
  }
  // layer 2 (tagbase 513: init publishes 514) + chunked classifier
  for (int c = 0; c < NCH; ++c) {
    gemm_gx<<<dim3(64, 16, 2), dim3(256), 0, stream>>>(
        out1, wihf2, wihb2, b_f2, b_b2, gxc, len, c * CH, 1024);
    lstm_scan<<<dim3(256), dim3(128), 0, stream>>>(
        gxc, whhf2, whhb2, len, nullptr, out2c, hbuf, cbuf, tags, c * CH, 513);
    gemm_cls<<<dim3(64, 1, 2), dim3(256), 0, stream>>>(
        out2c, wcls, (float*)d_out, len, c * CH);
  }
}